// Round 8
// baseline (2325.016 us; speedup 1.0000x reference)
//
#include <hip/hip_runtime.h>
#include <hip/hip_bf16.h>

// Transformer-XL forward, MI355X gfx950.
// Round 8: line-complete GEMM stores. Round 7 counters showed 26x HBM write
// amplification on proj4 (421 MB written for 16 MB of output) from partial
// 32B stores evicted before sibling stores merged. Fix: stage the C-tile in
// LDS (reusing K-loop buffers) and emit uint4/float4 stores where 8 lanes
// cover a full 128B line per instruction. Applied to proj4/ffn1/split-K.

#define BQ 2
#define QL 512
#define ML 512
#define CL 1024    // QLEN + MLEN
#define RL 1536    // CLEN + QLEN
#define HD 1024
#define NH 16
#define DH 64
#define FF 4096
#define NLAYER 4

typedef const float* FP;
typedef const __hip_bfloat16* BP;
typedef unsigned short u16;
typedef __attribute__((ext_vector_type(8))) __bf16 bf16x8;
typedef __attribute__((ext_vector_type(4))) float f32x4;

static __device__ __forceinline__ float b2f(__hip_bfloat16 x) { return __bfloat162float(x); }
static __device__ __forceinline__ u16 f2u(float f) {
    union { __hip_bfloat16 h; u16 u; } c; c.h = __float2bfloat16(f); return c.u;
}
static __device__ __forceinline__ float u2f(u16 u) {
    union { float f; unsigned int i; } c; c.i = ((unsigned int)u) << 16; return c.f;
}

// flags[0] = 1 if float inputs are fp32, 0 if bf16
// flags[1] = 1 if segment_matrix is int32, 0 if int8
__global__ void sniff_kernel(const unsigned int* __restrict__ ln1_gamma,
                             const unsigned char* __restrict__ seg,
                             int* __restrict__ flags) {
    if (threadIdx.x == 0) {
        flags[0] = (ln1_gamma[0] == 0x3F800000u) ? 1 : 0;
        int int32ok = 1;
        for (int i = 0; i < 256; ++i)
            if ((i & 3) != 0 && seg[i] != 0) { int32ok = 0; break; }
        flags[1] = int32ok;
    }
}

__global__ void canon_kernel(FP inf, BP inb, u16* __restrict__ out,
                             int n, const int* __restrict__ flags) {
    int i = blockIdx.x * 256 + threadIdx.x;
    if (i >= n) return;
    out[i] = flags[0] ? f2u(inf[i]) : ((const u16*)inb)[i];
}

__global__ void out_write_kernel(const u16* __restrict__ in, void* __restrict__ out,
                                 int n, const int* __restrict__ flags) {
    int i = blockIdx.x * 256 + threadIdx.x;
    if (i >= n) return;
    if (flags[0]) ((float*)out)[i] = u2f(in[i]);
    else          ((u16*)out)[i] = in[i];
}

// in: R x Cc (dual float), out: Cc x R bf16 (k-contiguous B^T)
__global__ __launch_bounds__(256) void transpose_kernel(
    FP inf, BP inb, u16* __restrict__ out, int R, int Cc,
    const int* __restrict__ flags) {
    __shared__ float t[32][33];
    const int tid = threadIdx.x;
    const int c0 = blockIdx.x * 32, r0 = blockIdx.y * 32;
    const int tc = tid & 31, tr = tid >> 5;
    const int f32 = flags[0];
    #pragma unroll
    for (int p = 0; p < 4; ++p) {
        int r = r0 + p * 8 + tr;
        size_t gi = (size_t)r * Cc + c0 + tc;
        t[p * 8 + tr][tc] = f32 ? inf[gi] : b2f(inb[gi]);
    }
    __syncthreads();
    #pragma unroll
    for (int p = 0; p < 4; ++p) {
        int c = c0 + p * 8 + tr;
        out[(size_t)c * R + r0 + tc] = f2u(t[tc][p * 8 + tr]);
    }
}

// context = concat(mems[l] (B,ML,H), X (B,QL,H)) -> (B,CL,H) bf16
__global__ void build_ctx_kernel(FP memf, BP memb, const u16* __restrict__ X,
                                 u16* __restrict__ CTX, const int* __restrict__ flags) {
    int i = blockIdx.x * 256 + threadIdx.x;
    int h = i % HD;
    int r = (i / HD) % CL;
    int b = i / (HD * CL);
    if (r < ML) {
        size_t mi = ((size_t)(b * ML + r)) * HD + h;
        CTX[i] = flags[0] ? f2u(memf[mi]) : ((const u16*)memb)[mi];
    } else {
        CTX[i] = X[((size_t)(b * QL + (r - ML))) * HD + h];
    }
}

// ---------------- shared 64x64 GEMM core ----------------
// acc(64x64) += A(64 x K, row stride lda) * Bt(64 x K, row stride ldb)^T
// Double-buffered LDS, one barrier per K-step, tile k+2 register prefetch.
// sA/sB: caller-provided LDS, 2*64*GPAD u16 each.
#define GPAD 72
#define GBUF (64 * GPAD)
__device__ __forceinline__ void gemm64_core(
    const u16* __restrict__ A, int lda, const u16* __restrict__ Bt, int ldb,
    int K, int tid, u16* sA, u16* sB, f32x4 (&acc)[2][2])
{
    const int lane = tid & 63, wv = tid >> 6;
    const int wm = (wv & 1) * 32, wn = (wv >> 1) * 32;
    const int lr = lane & 15, quad = lane >> 4;
    const int srow = tid >> 2, sch = tid & 3;
    const u16* Arow = A + (size_t)srow * lda + sch * 8;
    const u16* Brow = Bt + (size_t)srow * ldb + sch * 8;
    const int nk = K >> 6;

    uint4 ra[2][2], rb[2][2];
    #pragma unroll
    for (int p = 0; p < 2; ++p) {
        ra[0][p] = *(const uint4*)(Arow + p * 32);
        rb[0][p] = *(const uint4*)(Brow + p * 32);
    }
    if (nk > 1) {
        #pragma unroll
        for (int p = 0; p < 2; ++p) {
            ra[1][p] = *(const uint4*)(Arow + 64 + p * 32);
            rb[1][p] = *(const uint4*)(Brow + 64 + p * 32);
        }
    }
    #pragma unroll
    for (int p = 0; p < 2; ++p) {
        *(uint4*)&sA[0 * GBUF + srow * GPAD + p * 32 + sch * 8] = ra[0][p];
        *(uint4*)&sB[0 * GBUF + srow * GPAD + p * 32 + sch * 8] = rb[0][p];
    }

    for (int kt = 0; kt < nk; ++kt) {
        const int cur = kt & 1;
        __syncthreads();
        if (kt + 1 < nk) {
            const int nx = cur ^ 1;
            #pragma unroll
            for (int p = 0; p < 2; ++p) {
                *(uint4*)&sA[nx * GBUF + srow * GPAD + p * 32 + sch * 8] = ra[nx][p];
                *(uint4*)&sB[nx * GBUF + srow * GPAD + p * 32 + sch * 8] = rb[nx][p];
            }
        }
        if (kt + 2 < nk) {
            #pragma unroll
            for (int p = 0; p < 2; ++p) {
                ra[cur][p] = *(const uint4*)(Arow + (kt + 2) * 64 + p * 32);
                rb[cur][p] = *(const uint4*)(Brow + (kt + 2) * 64 + p * 32);
            }
        }
        bf16x8 af[2][2], bfm[2][2];
        #pragma unroll
        for (int mt = 0; mt < 2; ++mt)
            #pragma unroll
            for (int ks = 0; ks < 2; ++ks)
                af[mt][ks] = *(const bf16x8*)
                    &sA[cur * GBUF + (wm + mt * 16 + lr) * GPAD + ks * 32 + quad * 8];
        #pragma unroll
        for (int nt = 0; nt < 2; ++nt)
            #pragma unroll
            for (int ks = 0; ks < 2; ++ks)
                bfm[nt][ks] = *(const bf16x8*)
                    &sB[cur * GBUF + (wn + nt * 16 + lr) * GPAD + ks * 32 + quad * 8];
        #pragma unroll
        for (int mt = 0; mt < 2; ++mt)
            #pragma unroll
            for (int nt = 0; nt < 2; ++nt)
                #pragma unroll
                for (int ks = 0; ks < 2; ++ks)
                    acc[mt][nt] = __builtin_amdgcn_mfma_f32_16x16x32_bf16(
                        af[mt][ks], bfm[nt][ks], acc[mt][nt], 0, 0, 0);
    }
}

// stage bf16 C-tile in LDS, then stream out 128B-line-complete uint4 stores.
// st: u16 LDS, 64*GPAD capacity. vals already post-processed (bias/relu).
__device__ __forceinline__ void store_tile_bf16(
    u16* st, u16* __restrict__ C, int m0, int n0, int N, int tid,
    const f32x4 (&acc)[2][2], float bias0, float bias1, bool relu)
{
    const int lane = tid & 63, wv = tid >> 6;
    const int wm = (wv & 1) * 32, wn = (wv >> 1) * 32;
    const int lr = lane & 15, quad = lane >> 4;
    __syncthreads();                 // all waves done reading K-loop LDS
    #pragma unroll
    for (int nt = 0; nt < 2; ++nt) {
        float bv = nt ? bias1 : bias0;
        #pragma unroll
        for (int mt = 0; mt < 2; ++mt)
            #pragma unroll
            for (int r = 0; r < 4; ++r) {
                float v = acc[mt][nt][r] + bv;
                if (relu) v = fmaxf(v, 0.0f);
                st[(wm + mt * 16 + quad * 4 + r) * GPAD + wn + nt * 16 + lr] = f2u(v);
            }
    }
    __syncthreads();
    #pragma unroll
    for (int it = 0; it < 2; ++it) {  // 64 rows x 8 chunks of 8 u16
        int c = it * 256 + tid;
        int row = c >> 3, ch = c & 7;
        *(uint4*)&C[(size_t)(m0 + row) * N + n0 + ch * 8] =
            *(const uint4*)&st[row * GPAD + ch * 8];
    }
}

// same for fp32 partials (split-K). stf: float LDS, 64*68 capacity.
#define FPAD 68
__device__ __forceinline__ void store_tile_f32(
    float* stf, float* __restrict__ P, int m0, int n0, int N, int tid,
    const f32x4 (&acc)[2][2])
{
    const int lane = tid & 63, wv = tid >> 6;
    const int wm = (wv & 1) * 32, wn = (wv >> 1) * 32;
    const int lr = lane & 15, quad = lane >> 4;
    __syncthreads();
    #pragma unroll
    for (int nt = 0; nt < 2; ++nt)
        #pragma unroll
        for (int mt = 0; mt < 2; ++mt)
            #pragma unroll
            for (int r = 0; r < 4; ++r)
                stf[(wm + mt * 16 + quad * 4 + r) * FPAD + wn + nt * 16 + lr] =
                    acc[mt][nt][r];
    __syncthreads();
    #pragma unroll
    for (int it = 0; it < 4; ++it) {  // 64 rows x 16 chunks of 4 floats
        int c = it * 256 + tid;
        int row = c >> 4, ch = c & 15;
        *(float4*)&P[(size_t)(m0 + row) * N + n0 + ch * 4] =
            *(const float4*)&stf[row * FPAD + ch * 4];
    }
}

// ---------------- merged q/k/v/r projection GEMM ----------------
__global__ __launch_bounds__(256) void proj4_gemm(
    const u16* __restrict__ X, const u16* __restrict__ CTX,
    const u16* __restrict__ PE, const u16* __restrict__ W4,
    u16* __restrict__ Qb, u16* __restrict__ Kb,
    u16* __restrict__ Vb, u16* __restrict__ Rb)
{
    __shared__ __align__(16) u16 sA[2 * GBUF];
    __shared__ __align__(16) u16 sB[2 * GBUF];
    const int tid = threadIdx.x;
    const int by = blockIdx.y;
    const u16* Abase; u16* Cbase; int seg, mb;
    if (by < 16)      { seg = 0; Abase = X;   Cbase = Qb; mb = by; }
    else if (by < 48) { seg = 1; Abase = CTX; Cbase = Kb; mb = by - 16; }
    else if (by < 80) { seg = 2; Abase = CTX; Cbase = Vb; mb = by - 48; }
    else              { seg = 3; Abase = PE;  Cbase = Rb; mb = by - 80; }
    const int m0 = mb * 64, n0 = blockIdx.x * 64;

    f32x4 acc[2][2];
    #pragma unroll
    for (int mt = 0; mt < 2; ++mt)
        #pragma unroll
        for (int nt = 0; nt < 2; ++nt) acc[mt][nt] = (f32x4){0.f, 0.f, 0.f, 0.f};

    gemm64_core(Abase + (size_t)m0 * HD, HD,
                W4 + (size_t)seg * HD * HD + (size_t)n0 * HD, HD, HD, tid, sA, sB, acc);
    store_tile_bf16(sA, Cbase, m0, n0, HD, tid, acc, 0.f, 0.f, false);
}

// ---------------- plain 64x64 GEMM (FFN1: bias+relu) ----------------
template <bool RELU, bool HASBIAS>
__global__ __launch_bounds__(256) void mfma_gemm64(
    const u16* __restrict__ A, const u16* __restrict__ Bt,
    FP biasf, BP biasb, u16* __restrict__ C,
    int N, int K, const int* __restrict__ flags)
{
    __shared__ __align__(16) u16 sA[2 * GBUF];
    __shared__ __align__(16) u16 sB[2 * GBUF];
    const int tid = threadIdx.x;
    const int n0 = blockIdx.x * 64, m0 = blockIdx.y * 64;
    f32x4 acc[2][2];
    #pragma unroll
    for (int mt = 0; mt < 2; ++mt)
        #pragma unroll
        for (int nt = 0; nt < 2; ++nt) acc[mt][nt] = (f32x4){0.f, 0.f, 0.f, 0.f};

    gemm64_core(A + (size_t)m0 * K, K, Bt + (size_t)n0 * K, K, K, tid, sA, sB, acc);

    float b0 = 0.f, b1 = 0.f;
    if (HASBIAS) {
        const int lane = tid & 63, wv = tid >> 6;
        const int wn = (wv >> 1) * 32, lr = lane & 15;
        const int f32 = flags[0];
        b0 = f32 ? biasf[n0 + wn + lr] : b2f(biasb[n0 + wn + lr]);
        b1 = f32 ? biasf[n0 + wn + 16 + lr] : b2f(biasb[n0 + wn + 16 + lr]);
    }
    store_tile_bf16(sA, C, m0, n0, N, tid, acc, b0, b1, RELU);
}

// ---------------- split-K GEMM: fp32 partials ----------------
__global__ __launch_bounds__(256) void gemm64_splitk(
    const u16* __restrict__ A, const u16* __restrict__ Bt,
    float* __restrict__ part, int N, int Kfull, int Kc)
{
    __shared__ __align__(16) u16 sA[2 * GBUF];
    __shared__ __align__(16) u16 sB[2 * GBUF];
    __shared__ __align__(16) float stf[64 * FPAD];
    const int tid = threadIdx.x;
    const int n0 = blockIdx.x * 64, m0 = blockIdx.y * 64, z = blockIdx.z;
    f32x4 acc[2][2];
    #pragma unroll
    for (int mt = 0; mt < 2; ++mt)
        #pragma unroll
        for (int nt = 0; nt < 2; ++nt) acc[mt][nt] = (f32x4){0.f, 0.f, 0.f, 0.f};

    gemm64_core(A + (size_t)m0 * Kfull + z * Kc, Kfull,
                Bt + (size_t)n0 * Kfull + z * Kc, Kfull, Kc, tid, sA, sB, acc);
    store_tile_f32(stf, part + (size_t)z * (1024 * 1024), m0, n0, N, tid, acc);
}

// ---------------- reduce(4 partials) [+bias] + residual -> LayerNorm -> bf16 ----
template <bool HASBIAS>
__global__ __launch_bounds__(256) void reduce_add_ln(
    const float* __restrict__ part, FP biasf, BP biasb,
    const u16* __restrict__ resid, FP gf, BP gb, FP bef, BP beb,
    u16* __restrict__ O, const int* __restrict__ flags)
{
    const int row = blockIdx.x;               // B*QL rows of HD
    const int tid = threadIdx.x;
    const int wid = tid >> 6, lane = tid & 63;
    __shared__ float r1[4], r2[4];
    const int f32 = flags[0];
    float v[4];
    #pragma unroll
    for (int c = 0; c < 4; ++c) {
        int h = c * 256 + tid;
        size_t idx = (size_t)row * HD + h;
        float s = part[idx] + part[idx + 1048576] + part[idx + 2097152] + part[idx + 3145728];
        if (HASBIAS) s += f32 ? biasf[h] : b2f(biasb[h]);
        v[c] = s + u2f(resid[idx]);
    }
    float s = v[0] + v[1] + v[2] + v[3];
    #pragma unroll
    for (int o = 32; o > 0; o >>= 1) s += __shfl_xor(s, o);
    if (lane == 0) r1[wid] = s;
    __syncthreads();
    float mu = (r1[0] + r1[1] + r1[2] + r1[3]) * (1.0f / HD);
    float q = 0.f;
    #pragma unroll
    for (int c = 0; c < 4; ++c) { float d = v[c] - mu; q += d * d; }
    #pragma unroll
    for (int o = 32; o > 0; o >>= 1) q += __shfl_xor(q, o);
    if (lane == 0) r2[wid] = q;
    __syncthreads();
    float var = (r2[0] + r2[1] + r2[2] + r2[3]) * (1.0f / HD);
    float inv = rsqrtf(var + 1e-12f);
    #pragma unroll
    for (int c = 0; c < 4; ++c) {
        int h = c * 256 + tid;
        float g = f32 ? gf[h] : b2f(gb[h]);
        float be = f32 ? bef[h] : b2f(beb[h]);
        O[(size_t)row * HD + h] = f2u((v[c] - mu) * inv * g + be);
    }
}

// ---------------- ef2: (q + segment_bias) . segment_encoding[l] ----------------
__global__ void ef2_kernel(const u16* __restrict__ Qb, FP sbf, BP sbb,
                           FP sef, BP seb, float* __restrict__ EF,
                           const int* __restrict__ flags) {
    int t = blockIdx.x * 256 + threadIdx.x;
    if (t >= BQ * NH * QL) return;
    int i = t % QL;
    int n = (t / QL) % NH;
    int b = t / (QL * NH);
    float e0 = 0.f, e1 = 0.f;
    const int f32 = flags[0];
    for (int d = 0; d < DH; ++d) {
        float sbv = f32 ? sbf[n * DH + d] : b2f(sbb[n * DH + d]);
        float s0 = f32 ? sef[(0 * NH + n) * DH + d] : b2f(seb[(0 * NH + n) * DH + d]);
        float s1 = f32 ? sef[(1 * NH + n) * DH + d] : b2f(seb[(1 * NH + n) * DH + d]);
        float qv = u2f(Qb[((size_t)(b * QL + i) * NH + n) * DH + d]) + sbv;
        e0 += qv * s0;
        e1 += qv * s1;
    }
    EF[(size_t)t * 2 + 0] = e0;
    EF[(size_t)t * 2 + 1] = e1;
}

// ---------------- CK[bn][j] = cb_n . k_j ; PR[bn][rr] = pb_n . r_rr ----------------
__global__ void ckpr_kernel(const u16* __restrict__ Kb, const u16* __restrict__ Rb,
                            FP cbf, BP cbb, FP pbf, BP pbb,
                            float* __restrict__ CK, float* __restrict__ PR,
                            const int* __restrict__ flags) {
    int t = blockIdx.x * 256 + threadIdx.x;
    const int f32 = flags[0];
    if (t < 32 * CL) {
        int bn = t >> 10, j = t & (CL - 1);
        int b = bn >> 4, n = bn & 15;
        float s = 0.f;
        for (int d = 0; d < DH; ++d) {
            float c = f32 ? cbf[n * DH + d] : b2f(cbb[n * DH + d]);
            s += c * u2f(Kb[((size_t)(b * CL + j) * NH + n) * DH + d]);
        }
        CK[t] = s;
    } else {
        int t2 = t - 32 * CL;
        if (t2 >= 32 * RL) return;
        int bn = t2 / RL, rr = t2 % RL;
        int b = bn >> 4, n = bn & 15;
        float s = 0.f;
        for (int d = 0; d < DH; ++d) {
            float c = f32 ? pbf[n * DH + d] : b2f(pbb[n * DH + d]);
            s += c * u2f(Rb[((size_t)(b * RL + rr) * NH + n) * DH + d]);
        }
        PR[(size_t)bn * RL + rr] = s;
    }
}

// ---------------- MFMA scores ----------------
#define SPAD 72
__global__ __launch_bounds__(256) void scores_mfma(
    const u16* __restrict__ Qb, const u16* __restrict__ Kb,
    const u16* __restrict__ Rb, const float* __restrict__ CK,
    const float* __restrict__ PR, const float* __restrict__ EF,
    const void* __restrict__ seg, FP maskf, BP maskb,
    float* __restrict__ SC, const int* __restrict__ flags)
{
    __shared__ __align__(16) u16 sQ[64 * SPAD];
    __shared__ __align__(16) u16 sKR[192 * SPAD];
    __shared__ float sD2[4 * 16 * 132];
    const int tid = threadIdx.x;
    const int j0 = blockIdx.x * 64;
    const int i0 = blockIdx.y * 64;
    const int bn = blockIdx.z, b = bn >> 4, n = bn & 15;
    const int lane = tid & 63, w = tid >> 6;
    const int lr = lane & 15, quad = lane >> 4;
    const int baseR = 449 - i0 + j0;   // rr at p=0; in [1, 1409]

    #pragma unroll
    for (int p = 0; p < 2; ++p) {
        int c = p * 256 + tid;
        int row = c >> 3, ch = c & 7;
        *(uint4*)&sQ[row * SPAD + ch * 8] =
            *(const uint4*)&Qb[((size_t)(b * QL + i0 + row) * NH + n) * DH + ch * 8];
    }
    #pragma unroll
    for (int p = 0; p < 6; ++p) {
        int c = p * 256 + tid;
        int row = c >> 3, ch = c & 7;
        const u16* src;
        if (row < 64) {
            src = &Kb[((size_t)(b * CL + j0 + row) * NH + n) * DH + ch * 8];
        } else {
            int rr = baseR + row - 64;
            rr = rr < 0 ? 0 : (rr > RL - 1 ? RL - 1 : rr);
            src = &Rb[((size_t)(b * RL + rr) * NH + n) * DH + ch * 8];
        }
        *(uint4*)&sKR[row * SPAD + ch * 8] = *(const uint4*)src;
    }
    __syncthreads();

    f32x4 acc[12];
    #pragma unroll
    for (int i = 0; i < 12; ++i) acc[i] = (f32x4){0.f, 0.f, 0.f, 0.f};
    #pragma unroll
    for (int ks = 0; ks < 2; ++ks) {
        bf16x8 a = *(const bf16x8*)&sQ[(w * 16 + lr) * SPAD + ks * 32 + quad * 8];
        #pragma unroll
        for (int ct = 0; ct < 12; ++ct) {
            bf16x8 bfrag = *(const bf16x8*)&sKR[(ct * 16 + lr) * SPAD + ks * 32 + quad * 8];
            acc[ct] = __builtin_amdgcn_mfma_f32_16x16x32_bf16(a, bfrag, acc[ct], 0, 0, 0);
        }
    }

    float* myD = &sD2[w * 16 * 132];
    #pragma unroll
    for (int ct = 4; ct < 12; ++ct) {
        int pt = (ct - 4) * 16;
        #pragma unroll
        for (int r = 0; r < 4; ++r)
            myD[(quad * 4 + r) * 132 + pt + lr] = acc[ct][r];
    }
    __syncthreads();

    const int f32 = flags[0], s32 = flags[1];
    #pragma unroll
    for (int ct = 0; ct < 4; ++ct) {
        int jl = ct * 16 + lr, j = j0 + jl;
        float ckv = CK[(size_t)bn * CL + j];
        #pragma unroll
        for (int r = 0; r < 4; ++r) {
            int ilw = quad * 4 + r;
            int il = w * 16 + ilw;
            int i = i0 + il;
            int p = 63 - il + jl;            // in [0,126]
            float bd = myD[ilw * 132 + p];
            float pr = PR[(size_t)bn * RL + baseR + p];
            size_t mi = ((size_t)b * QL + i) * CL + j;
            int sv = s32 ? ((const int*)seg)[mi] : (int)((const signed char*)seg)[mi];
            float ef = EF[((size_t)bn * QL + i) * 2 + (sv ? 1 : 0)];
            float mk = f32 ? maskf[mi] : b2f(maskb[mi]);
            SC[((size_t)bn * QL + i) * CL + j] =
                (acc[ct][r] + bd + ckv + pr + ef) * 0.125f + mk * -1e30f;
        }
    }
}

// ---------------- softmax (CL=1024): fp32 in, bf16 probs in-place ----------------
__global__ __launch_bounds__(256) void softmax_kernel(float* __restrict__ SC) {
    const int row = blockIdx.x;
    float* p = SC + (size_t)row * CL;
    const int tid = threadIdx.x;
    const int wid = tid >> 6, lane = tid & 63;
    __shared__ float r1[4], r2[4];
    float v[4];
    #pragma unroll
    for (int c = 0; c < 4; ++c) v[c] = p[c * 256 + tid];
    float mx = fmaxf(fmaxf(v[0], v[1]), fmaxf(v[2], v[3]));
    #pragma unroll
    for (int o = 32; o > 0; o >>= 1) mx = fmaxf(mx, __shfl_xor(mx, o));
    if (lane == 0) r1[wid] = mx;
    __syncthreads();
    mx = fmaxf(fmaxf(r1[0], r1[1]), fmaxf(r1[2], r1[3]));
    float s = 0.f;
    #pragma unroll
    for (int c = 0; c < 4; ++c) { v[c] = __expf(v[c] - mx); s += v[c]; }
    #pragma unroll
    for (int o = 32; o > 0; o >>= 1) s += __shfl_xor(s, o);
    if (lane == 0) r2[wid] = s;
    __syncthreads();
    s = r2[0] + r2[1] + r2[2] + r2[3];
    float inv = 1.0f / s;
    u16* pb = (u16*)p;
    #pragma unroll
    for (int c = 0; c < 4; ++c) pb[c * 256 + tid] = f2u(v[c] * inv);
}

// ---------------- MFMA attn = probs(bf16) @ V, per (b,n) ----------------
#define VPAD 40
__global__ __launch_bounds__(256) void attn_v_mfma(
    const u16* __restrict__ PB, const u16* __restrict__ Vb, u16* __restrict__ AT)
{
    __shared__ __align__(16) u16 sP[32 * VPAD];
    __shared__ __align__(16) u16 sV[64 * VPAD];
    const int tid = threadIdx.x;
    const int i0 = blockIdx.x * 32;
    const int bn = blockIdx.y, b = bn >> 4, n = bn & 15;
    const int lane = tid & 63, w = tid >> 6;
    const int lr = lane & 15, quad = lane >> 4;
    const int rt = w >> 1;
    const int ct0 = (w & 1) * 2;
    const u16* Prow = PB + (size_t)bn * QL * 2 * CL;
    f32x4 acc[2];
    acc[0] = (f32x4){0.f, 0.f, 0.f, 0.f};
    acc[1] = (f32x4){0.f, 0.f, 0.f, 0.f};

    for (int k0 = 0; k0 < CL; k0 += 32) {
        if (tid < 128) {
            int row = tid >> 2, ch = tid & 3;
            *(uint4*)&sP[row * VPAD + ch * 8] =
                *(const uint4*)&Prow[(size_t)(i0 + row) * 2 * CL + k0 + ch * 8];
        }
        {
            int j = tid >> 3, d0 = (tid & 7) * 8;
            u16 tmp[8];
            *(uint4*)tmp = *(const uint4*)&Vb[((size_t)(b * CL + k0 + j) * NH + n) * DH + d0];
            #pragma unroll
            for (int q2 = 0; q2 < 8; ++q2) sV[(d0 + q2) * VPAD + j] = tmp[q2];
        }
        __syncthreads();
        bf16x8 a = *(const bf16x8*)&sP[(rt * 16 + lr) * VPAD + quad * 8];
        #pragma unroll
        for (int c = 0; c < 2; ++c) {
            bf16x8 bfrag = *(const bf16x8*)&sV[((ct0 + c) * 16 + lr) * VPAD + quad * 8];
            acc[c] = __builtin_amdgcn_mfma_f32_16x16x32_bf16(a, bfrag, acc[c], 0, 0, 0);
        }
        __syncthreads();
    }
    #pragma unroll
    for (int c = 0; c < 2; ++c) {
        int d = (ct0 + c) * 16 + lr;
        #pragma unroll
        for (int r = 0; r < 4; ++r) {
            int i = i0 + rt * 16 + quad * 4 + r;
            AT[((size_t)(b * QL + i) * NH + n) * DH + d] = f2u(acc[c][r]);
        }
    }
}

extern "C" void kernel_launch(void* const* d_in, const int* in_sizes, int n_in,
                              void* d_out, int out_size, void* d_ws, size_t ws_size,
                              hipStream_t stream) {
    (void)in_sizes; (void)n_in; (void)out_size; (void)ws_size;
    const void* content_stream = d_in[0];
    const void* content_mask   = d_in[1];
    const void* pos_enc        = d_in[2];
    const void* seg_mat        = d_in[3];
    const void* mems           = d_in[4];
    const void* w_q            = d_in[5];
    const void* w_k            = d_in[6];
    const void* w_v            = d_in[7];
    const void* w_r            = d_in[8];
    const void* w_o            = d_in[9];
    const void* ffn_w1         = d_in[10];
    const void* ffn_b1         = d_in[11];
    const void* ffn_w2         = d_in[12];
    const void* ffn_b2         = d_in[13];
    const void* ln1_g          = d_in[14];
    const void* ln1_b          = d_in[15];
    const void* ln2_g          = d_in[16];
    const void* ln2_b          = d_in[17];
    const void* cb             = d_in[18];
    const void* pb             = d_in[19];
    const void* sb             = d_in[20];
    const void* se             = d_in[21];

    float* SC    = (float*)d_ws;              // scores / bf16 probs / F1 / PART
    float* PART  = SC + 4194304;              // 4M f32 partials (probs dead by then)
    float* EF    = SC + 16777216;
    float* CK    = EF + 32768;
    float* PR    = CK + 32768;
    int*   flags = (int*)(PR + 49152);
    u16*   bws   = (u16*)(flags + 16);

    u16* X   = bws;               u16* Y   = X   + 1048576;
    u16* CTX = Y   + 1048576;     u16* Qb  = CTX + 2097152;
    u16* Kb  = Qb  + 1048576;     u16* Vb  = Kb  + 2097152;
    u16* Rb  = Vb  + 2097152;     u16* PE  = Rb  + 3145728;
    u16* AT  = PE  + 3145728;
    u16* W4  = AT  + 1048576;     // WQT|WKT|WVT|WRT contiguous
    u16* WOc = W4  + 4194304;     u16* W1T = WOc + 1048576;
    u16* W2T = W1T + 4194304;
    u16* F1  = (u16*)SC;          // alias: probs/scores consumed before FFN1 writes

    const size_t wstride   = (size_t)HD * HD;
    const size_t memstride = (size_t)BQ * ML * HD;

    const dim3 blk(256);
    #define DUAL(base, off) ((FP)(base) + (off)), ((BP)(base) + (off))

    sniff_kernel<<<dim3(1), dim3(64), 0, stream>>>(
        (const unsigned int*)ln1_g, (const unsigned char*)seg_mat, flags);

    canon_kernel<<<dim3((BQ * QL * HD) / 256), blk, 0, stream>>>(
        DUAL(content_stream, 0), X, BQ * QL * HD, flags);
    canon_kernel<<<dim3((BQ * RL * HD) / 256), blk, 0, stream>>>(
        DUAL(pos_enc, 0), PE, BQ * RL * HD, flags);

    for (int l = 0; l < NLAYER; ++l) {
        transpose_kernel<<<dim3(32, 32), blk, 0, stream>>>(
            DUAL(w_q, (size_t)l * wstride), W4, HD, HD, flags);
        transpose_kernel<<<dim3(32, 32), blk, 0, stream>>>(
            DUAL(w_k, (size_t)l * wstride), W4 + 1048576, HD, HD, flags);
        transpose_kernel<<<dim3(32, 32), blk, 0, stream>>>(
            DUAL(w_v, (size_t)l * wstride), W4 + 2097152, HD, HD, flags);
        transpose_kernel<<<dim3(32, 32), blk, 0, stream>>>(
            DUAL(w_r, (size_t)l * wstride), W4 + 3145728, HD, HD, flags);
        canon_kernel<<<dim3((HD * HD) / 256), blk, 0, stream>>>(
            DUAL(w_o, (size_t)l * wstride), WOc, HD * HD, flags);
        transpose_kernel<<<dim3(FF / 32, HD / 32), blk, 0, stream>>>(
            DUAL(ffn_w1, (size_t)l * HD * FF), W1T, HD, FF, flags);
        transpose_kernel<<<dim3(HD / 32, FF / 32), blk, 0, stream>>>(
            DUAL(ffn_w2, (size_t)l * FF * HD), W2T, FF, HD, flags);

        build_ctx_kernel<<<dim3((BQ * CL * HD) / 256), blk, 0, stream>>>(
            DUAL(mems, (size_t)l * memstride), X, CTX, flags);

        proj4_gemm<<<dim3(16, 128), blk, 0, stream>>>(
            X, CTX, PE, W4, Qb, Kb, Vb, Rb);

        ef2_kernel<<<dim3((BQ * NH * QL) / 256), blk, 0, stream>>>(
            Qb, DUAL(sb, 0), DUAL(se, (size_t)l * 2 * NH * DH), EF, flags);
        ckpr_kernel<<<dim3((32 * CL + 32 * RL) / 256), blk, 0, stream>>>(
            Kb, Rb, DUAL(cb, 0), DUAL(pb, 0), CK, PR, flags);

        scores_mfma<<<dim3(CL / 64, QL / 64, BQ * NH), blk, 0, stream>>>(
            Qb, Kb, Rb, CK, PR, EF, seg_mat, DUAL(content_mask, 0), SC, flags);

        softmax_kernel<<<dim3(BQ * NH * QL), blk, 0, stream>>>(SC);

        attn_v_mfma<<<dim3(QL / 32, BQ * NH), blk, 0, stream>>>(
            (const u16*)SC, Vb, AT);

        gemm64_splitk<<<dim3(16, 16, 4), blk, 0, stream>>>(
            AT, WOc, PART, HD, HD, 256);
        reduce_add_ln<false><<<dim3(BQ * QL), blk, 0, stream>>>(
            PART, (FP)nullptr, (BP)nullptr, X,
            DUAL(ln1_g, (size_t)l * HD), DUAL(ln1_b, (size_t)l * HD), Y, flags);

        mfma_gemm64<true, true><<<dim3(FF / 64, (BQ * QL) / 64), blk, 0, stream>>>(
            Y, W1T, DUAL(ffn_b1, (size_t)l * FF), F1, FF, HD, flags);

        gemm64_splitk<<<dim3(16, 16, 4), blk, 0, stream>>>(
            F1, W2T, PART, HD, FF, 1024);
        reduce_add_ln<true><<<dim3(BQ * QL), blk, 0, stream>>>(
            PART, DUAL(ffn_b2, (size_t)l * HD), Y,
            DUAL(ln2_g, (size_t)l * HD), DUAL(ln2_b, (size_t)l * HD), X, flags);
    }
    #undef DUAL

    out_write_kernel<<<dim3((BQ * QL * HD) / 256), blk, 0, stream>>>(
        X, d_out, BQ * QL * HD, flags);
}

// Round 9
// 1422.550 us; speedup vs baseline: 1.6344x; 1.6344x over previous
//
#include <hip/hip_runtime.h>
#include <hip/hip_bf16.h>

// Transformer-XL forward, MI355X gfx950.
// Round 9: GEMM core reverted to 128x128/BK=32 tiles (4x less aggregate L2
// traffic than 64x64 — round 8 falsified the store-granularity theory) and
// staged via __builtin_amdgcn_global_load_lds width=16 (m97 recipe: async
// DMA to LDS, wave-uniform base + lane*16B, unpadded 32-elem rows). Merged
// proj4 grid and split-K o/FFN2 retained. Direct epilogue stores.

#define BQ 2
#define QL 512
#define ML 512
#define CL 1024    // QLEN + MLEN
#define RL 1536    // CLEN + QLEN
#define HD 1024
#define NH 16
#define DH 64
#define FF 4096
#define NLAYER 4

typedef const float* FP;
typedef const __hip_bfloat16* BP;
typedef unsigned short u16;
typedef __attribute__((ext_vector_type(8))) __bf16 bf16x8;
typedef __attribute__((ext_vector_type(4))) float f32x4;

static __device__ __forceinline__ float b2f(__hip_bfloat16 x) { return __bfloat162float(x); }
static __device__ __forceinline__ u16 f2u(float f) {
    union { __hip_bfloat16 h; u16 u; } c; c.h = __float2bfloat16(f); return c.u;
}
static __device__ __forceinline__ float u2f(u16 u) {
    union { float f; unsigned int i; } c; c.i = ((unsigned int)u) << 16; return c.f;
}

// async 16B global->LDS (gfx950). Per-lane global addr; LDS dest must equal
// wave-uniform base + lane*16B in the exact lane order.
static __device__ __forceinline__ void gll16(const u16* g, u16* l) {
    __builtin_amdgcn_global_load_lds(
        (__attribute__((address_space(1))) void*)(u16*)g,
        (__attribute__((address_space(3))) void*)l, 16, 0, 0);
}

// flags[0] = 1 if float inputs are fp32, 0 if bf16
// flags[1] = 1 if segment_matrix is int32, 0 if int8
__global__ void sniff_kernel(const unsigned int* __restrict__ ln1_gamma,
                             const unsigned char* __restrict__ seg,
                             int* __restrict__ flags) {
    if (threadIdx.x == 0) {
        flags[0] = (ln1_gamma[0] == 0x3F800000u) ? 1 : 0;
        int int32ok = 1;
        for (int i = 0; i < 256; ++i)
            if ((i & 3) != 0 && seg[i] != 0) { int32ok = 0; break; }
        flags[1] = int32ok;
    }
}

__global__ void canon_kernel(FP inf, BP inb, u16* __restrict__ out,
                             int n, const int* __restrict__ flags) {
    int i = blockIdx.x * 256 + threadIdx.x;
    if (i >= n) return;
    out[i] = flags[0] ? f2u(inf[i]) : ((const u16*)inb)[i];
}

__global__ void out_write_kernel(const u16* __restrict__ in, void* __restrict__ out,
                                 int n, const int* __restrict__ flags) {
    int i = blockIdx.x * 256 + threadIdx.x;
    if (i >= n) return;
    if (flags[0]) ((float*)out)[i] = u2f(in[i]);
    else          ((u16*)out)[i] = in[i];
}

// in: R x Cc (dual float), out: Cc x R bf16 (k-contiguous B^T)
__global__ __launch_bounds__(256) void transpose_kernel(
    FP inf, BP inb, u16* __restrict__ out, int R, int Cc,
    const int* __restrict__ flags) {
    __shared__ float t[32][33];
    const int tid = threadIdx.x;
    const int c0 = blockIdx.x * 32, r0 = blockIdx.y * 32;
    const int tc = tid & 31, tr = tid >> 5;
    const int f32 = flags[0];
    #pragma unroll
    for (int p = 0; p < 4; ++p) {
        int r = r0 + p * 8 + tr;
        size_t gi = (size_t)r * Cc + c0 + tc;
        t[p * 8 + tr][tc] = f32 ? inf[gi] : b2f(inb[gi]);
    }
    __syncthreads();
    #pragma unroll
    for (int p = 0; p < 4; ++p) {
        int c = c0 + p * 8 + tr;
        out[(size_t)c * R + r0 + tc] = f2u(t[tc][p * 8 + tr]);
    }
}

// context = concat(mems[l] (B,ML,H), X (B,QL,H)) -> (B,CL,H) bf16
__global__ void build_ctx_kernel(FP memf, BP memb, const u16* __restrict__ X,
                                 u16* __restrict__ CTX, const int* __restrict__ flags) {
    int i = blockIdx.x * 256 + threadIdx.x;
    int h = i % HD;
    int r = (i / HD) % CL;
    int b = i / (HD * CL);
    if (r < ML) {
        size_t mi = ((size_t)(b * ML + r)) * HD + h;
        CTX[i] = flags[0] ? f2u(memf[mi]) : ((const u16*)memb)[mi];
    } else {
        CTX[i] = X[((size_t)(b * QL + (r - ML))) * HD + h];
    }
}

// ---------------- 128x128 GEMM core, BK=32, async LDS staging ----------------
// acc(128x128; wave w owns 64x64) += A(128 x K, stride lda) * Bt(128 x K)^T.
// sA/sB: 128*32 u16, unpadded rows of 32 elems (global_load_lds lane order).
__device__ __forceinline__ void gemm128_core(
    const u16* __restrict__ A, int lda, const u16* __restrict__ Bt, int ldb,
    int K, int tid, u16* sA, u16* sB, f32x4 (&acc)[4][4])
{
    const int lane = tid & 63, w = tid >> 6;
    const int wm = (w & 1) * 64, wn = (w >> 1) * 64;
    const int lr = lane & 15, quad = lane >> 4;
    const int srow = lane >> 2;           // 16 rows per instr, 4 lanes/row
    const int sch = (lane & 3) * 8;       // 8 u16 = 16B per lane

    for (int k0 = 0; k0 < K; k0 += 32) {
        #pragma unroll
        for (int j = 0; j < 2; ++j) {     // wave w stages rows w*32+j*16 .. +15
            int rb = w * 32 + j * 16;
            gll16(&A[(size_t)(rb + srow) * lda + k0 + sch], &sA[rb * 32 + lane * 8]);
            gll16(&Bt[(size_t)(rb + srow) * ldb + k0 + sch], &sB[rb * 32 + lane * 8]);
        }
        __syncthreads();                  // drains vmcnt, then barrier
        bf16x8 af[4], bf[4];
        #pragma unroll
        for (int mi = 0; mi < 4; ++mi)
            af[mi] = *(const bf16x8*)&sA[(wm + mi * 16 + lr) * 32 + quad * 8];
        #pragma unroll
        for (int ni = 0; ni < 4; ++ni)
            bf[ni] = *(const bf16x8*)&sB[(wn + ni * 16 + lr) * 32 + quad * 8];
        #pragma unroll
        for (int mi = 0; mi < 4; ++mi)
            #pragma unroll
            for (int ni = 0; ni < 4; ++ni)
                acc[mi][ni] = __builtin_amdgcn_mfma_f32_16x16x32_bf16(
                    af[mi], bf[ni], acc[mi][ni], 0, 0, 0);
        __syncthreads();
    }
}

#define ACC_INIT(acc) \
    _Pragma("unroll") for (int mi = 0; mi < 4; ++mi) \
        _Pragma("unroll") for (int ni = 0; ni < 4; ++ni) \
            acc[mi][ni] = (f32x4){0.f, 0.f, 0.f, 0.f};

// ---------------- merged q/k/v/r projection GEMM (128-tile) ----------------
// grid (8, 64). Segments along y: q 8, k 16, v 16, r 24 m-blocks.
__global__ __launch_bounds__(256) void proj4_gemm(
    const u16* __restrict__ X, const u16* __restrict__ CTX,
    const u16* __restrict__ PE, const u16* __restrict__ W4,
    u16* __restrict__ Qb, u16* __restrict__ Kb,
    u16* __restrict__ Vb, u16* __restrict__ Rb)
{
    __shared__ __align__(16) u16 sA[128 * 32];
    __shared__ __align__(16) u16 sB[128 * 32];
    const int tid = threadIdx.x;
    const int by = blockIdx.y;
    const u16* Abase; u16* Cbase; int seg, mb;
    if (by < 8)       { seg = 0; Abase = X;   Cbase = Qb; mb = by; }
    else if (by < 24) { seg = 1; Abase = CTX; Cbase = Kb; mb = by - 8; }
    else if (by < 40) { seg = 2; Abase = CTX; Cbase = Vb; mb = by - 24; }
    else              { seg = 3; Abase = PE;  Cbase = Rb; mb = by - 40; }
    const int m0 = mb * 128, n0 = blockIdx.x * 128;

    f32x4 acc[4][4];
    ACC_INIT(acc)
    gemm128_core(Abase + (size_t)m0 * HD, HD,
                 W4 + (size_t)seg * HD * HD + (size_t)n0 * HD, HD, HD,
                 tid, sA, sB, acc);

    const int lane = tid & 63, w = tid >> 6;
    const int wm = (w & 1) * 64, wn = (w >> 1) * 64;
    const int lr = lane & 15, quad = lane >> 4;
    #pragma unroll
    for (int ni = 0; ni < 4; ++ni) {
        int col = n0 + wn + ni * 16 + lr;
        #pragma unroll
        for (int mi = 0; mi < 4; ++mi) {
            int row = m0 + wm + mi * 16 + quad * 4;
            #pragma unroll
            for (int r = 0; r < 4; ++r)
                Cbase[(size_t)(row + r) * HD + col] = f2u(acc[mi][ni][r]);
        }
    }
}

// ---------------- plain 128-tile GEMM (FFN1: bias+relu) ----------------
template <bool RELU, bool HASBIAS>
__global__ __launch_bounds__(256) void mfma_gemm128(
    const u16* __restrict__ A, const u16* __restrict__ Bt,
    FP biasf, BP biasb, u16* __restrict__ C,
    int N, int K, const int* __restrict__ flags)
{
    __shared__ __align__(16) u16 sA[128 * 32];
    __shared__ __align__(16) u16 sB[128 * 32];
    const int tid = threadIdx.x;
    const int n0 = blockIdx.x * 128, m0 = blockIdx.y * 128;
    f32x4 acc[4][4];
    ACC_INIT(acc)
    gemm128_core(A + (size_t)m0 * K, K, Bt + (size_t)n0 * K, K, K,
                 tid, sA, sB, acc);

    const int lane = tid & 63, w = tid >> 6;
    const int wm = (w & 1) * 64, wn = (w >> 1) * 64;
    const int lr = lane & 15, quad = lane >> 4;
    const int f32 = flags[0];
    #pragma unroll
    for (int ni = 0; ni < 4; ++ni) {
        int col = n0 + wn + ni * 16 + lr;
        float bv = 0.f;
        if (HASBIAS) bv = f32 ? biasf[col] : b2f(biasb[col]);
        #pragma unroll
        for (int mi = 0; mi < 4; ++mi) {
            int row = m0 + wm + mi * 16 + quad * 4;
            #pragma unroll
            for (int r = 0; r < 4; ++r) {
                float v = acc[mi][ni][r];
                if (HASBIAS) v += bv;
                if (RELU) v = fmaxf(v, 0.0f);
                C[(size_t)(row + r) * N + col] = f2u(v);
            }
        }
    }
}

// ---------------- split-K 128-tile GEMM: fp32 partials ----------------
// grid (N/128, M/128, S). part[z][m][n], z-stride 1024*1024 (M=N=1024).
__global__ __launch_bounds__(256) void gemm128_splitk(
    const u16* __restrict__ A, const u16* __restrict__ Bt,
    float* __restrict__ part, int N, int Kfull, int Kc)
{
    __shared__ __align__(16) u16 sA[128 * 32];
    __shared__ __align__(16) u16 sB[128 * 32];
    const int tid = threadIdx.x;
    const int n0 = blockIdx.x * 128, m0 = blockIdx.y * 128, z = blockIdx.z;
    f32x4 acc[4][4];
    ACC_INIT(acc)
    gemm128_core(A + (size_t)m0 * Kfull + z * Kc, Kfull,
                 Bt + (size_t)n0 * Kfull + z * Kc, Kfull, Kc,
                 tid, sA, sB, acc);

    float* P = part + (size_t)z * (1024 * 1024);
    const int lane = tid & 63, w = tid >> 6;
    const int wm = (w & 1) * 64, wn = (w >> 1) * 64;
    const int lr = lane & 15, quad = lane >> 4;
    #pragma unroll
    for (int ni = 0; ni < 4; ++ni) {
        int col = n0 + wn + ni * 16 + lr;
        #pragma unroll
        for (int mi = 0; mi < 4; ++mi) {
            int row = m0 + wm + mi * 16 + quad * 4;
            #pragma unroll
            for (int r = 0; r < 4; ++r)
                P[(size_t)(row + r) * N + col] = acc[mi][ni][r];
        }
    }
}

// ---------------- reduce(4 partials) [+bias] + residual -> LayerNorm -> bf16 ----
template <bool HASBIAS>
__global__ __launch_bounds__(256) void reduce_add_ln(
    const float* __restrict__ part, FP biasf, BP biasb,
    const u16* __restrict__ resid, FP gf, BP gb, FP bef, BP beb,
    u16* __restrict__ O, const int* __restrict__ flags)
{
    const int row = blockIdx.x;               // B*QL rows of HD
    const int tid = threadIdx.x;
    const int wid = tid >> 6, lane = tid & 63;
    __shared__ float r1[4], r2[4];
    const int f32 = flags[0];
    float v[4];
    #pragma unroll
    for (int c = 0; c < 4; ++c) {
        int h = c * 256 + tid;
        size_t idx = (size_t)row * HD + h;
        float s = part[idx] + part[idx + 1048576] + part[idx + 2097152] + part[idx + 3145728];
        if (HASBIAS) s += f32 ? biasf[h] : b2f(biasb[h]);
        v[c] = s + u2f(resid[idx]);
    }
    float s = v[0] + v[1] + v[2] + v[3];
    #pragma unroll
    for (int o = 32; o > 0; o >>= 1) s += __shfl_xor(s, o);
    if (lane == 0) r1[wid] = s;
    __syncthreads();
    float mu = (r1[0] + r1[1] + r1[2] + r1[3]) * (1.0f / HD);
    float q = 0.f;
    #pragma unroll
    for (int c = 0; c < 4; ++c) { float d = v[c] - mu; q += d * d; }
    #pragma unroll
    for (int o = 32; o > 0; o >>= 1) q += __shfl_xor(q, o);
    if (lane == 0) r2[wid] = q;
    __syncthreads();
    float var = (r2[0] + r2[1] + r2[2] + r2[3]) * (1.0f / HD);
    float inv = rsqrtf(var + 1e-12f);
    #pragma unroll
    for (int c = 0; c < 4; ++c) {
        int h = c * 256 + tid;
        float g = f32 ? gf[h] : b2f(gb[h]);
        float be = f32 ? bef[h] : b2f(beb[h]);
        O[(size_t)row * HD + h] = f2u((v[c] - mu) * inv * g + be);
    }
}

// ---------------- ef2: (q + segment_bias) . segment_encoding[l] ----------------
__global__ void ef2_kernel(const u16* __restrict__ Qb, FP sbf, BP sbb,
                           FP sef, BP seb, float* __restrict__ EF,
                           const int* __restrict__ flags) {
    int t = blockIdx.x * 256 + threadIdx.x;
    if (t >= BQ * NH * QL) return;
    int i = t % QL;
    int n = (t / QL) % NH;
    int b = t / (QL * NH);
    float e0 = 0.f, e1 = 0.f;
    const int f32 = flags[0];
    for (int d = 0; d < DH; ++d) {
        float sbv = f32 ? sbf[n * DH + d] : b2f(sbb[n * DH + d]);
        float s0 = f32 ? sef[(0 * NH + n) * DH + d] : b2f(seb[(0 * NH + n) * DH + d]);
        float s1 = f32 ? sef[(1 * NH + n) * DH + d] : b2f(seb[(1 * NH + n) * DH + d]);
        float qv = u2f(Qb[((size_t)(b * QL + i) * NH + n) * DH + d]) + sbv;
        e0 += qv * s0;
        e1 += qv * s1;
    }
    EF[(size_t)t * 2 + 0] = e0;
    EF[(size_t)t * 2 + 1] = e1;
}

// ---------------- CK[bn][j] = cb_n . k_j ; PR[bn][rr] = pb_n . r_rr ----------------
__global__ void ckpr_kernel(const u16* __restrict__ Kb, const u16* __restrict__ Rb,
                            FP cbf, BP cbb, FP pbf, BP pbb,
                            float* __restrict__ CK, float* __restrict__ PR,
                            const int* __restrict__ flags) {
    int t = blockIdx.x * 256 + threadIdx.x;
    const int f32 = flags[0];
    if (t < 32 * CL) {
        int bn = t >> 10, j = t & (CL - 1);
        int b = bn >> 4, n = bn & 15;
        float s = 0.f;
        for (int d = 0; d < DH; ++d) {
            float c = f32 ? cbf[n * DH + d] : b2f(cbb[n * DH + d]);
            s += c * u2f(Kb[((size_t)(b * CL + j) * NH + n) * DH + d]);
        }
        CK[t] = s;
    } else {
        int t2 = t - 32 * CL;
        if (t2 >= 32 * RL) return;
        int bn = t2 / RL, rr = t2 % RL;
        int b = bn >> 4, n = bn & 15;
        float s = 0.f;
        for (int d = 0; d < DH; ++d) {
            float c = f32 ? pbf[n * DH + d] : b2f(pbb[n * DH + d]);
            s += c * u2f(Rb[((size_t)(b * RL + rr) * NH + n) * DH + d]);
        }
        PR[(size_t)bn * RL + rr] = s;
    }
}

// ---------------- MFMA scores ----------------
#define SPAD 72
__global__ __launch_bounds__(256) void scores_mfma(
    const u16* __restrict__ Qb, const u16* __restrict__ Kb,
    const u16* __restrict__ Rb, const float* __restrict__ CK,
    const float* __restrict__ PR, const float* __restrict__ EF,
    const void* __restrict__ seg, FP maskf, BP maskb,
    float* __restrict__ SC, const int* __restrict__ flags)
{
    __shared__ __align__(16) u16 sQ[64 * SPAD];
    __shared__ __align__(16) u16 sKR[192 * SPAD];
    __shared__ float sD2[4 * 16 * 132];
    const int tid = threadIdx.x;
    const int j0 = blockIdx.x * 64;
    const int i0 = blockIdx.y * 64;
    const int bn = blockIdx.z, b = bn >> 4, n = bn & 15;
    const int lane = tid & 63, w = tid >> 6;
    const int lr = lane & 15, quad = lane >> 4;
    const int baseR = 449 - i0 + j0;   // rr at p=0; in [1, 1409]

    #pragma unroll
    for (int p = 0; p < 2; ++p) {
        int c = p * 256 + tid;
        int row = c >> 3, ch = c & 7;
        *(uint4*)&sQ[row * SPAD + ch * 8] =
            *(const uint4*)&Qb[((size_t)(b * QL + i0 + row) * NH + n) * DH + ch * 8];
    }
    #pragma unroll
    for (int p = 0; p < 6; ++p) {
        int c = p * 256 + tid;
        int row = c >> 3, ch = c & 7;
        const u16* src;
        if (row < 64) {
            src = &Kb[((size_t)(b * CL + j0 + row) * NH + n) * DH + ch * 8];
        } else {
            int rr = baseR + row - 64;
            rr = rr < 0 ? 0 : (rr > RL - 1 ? RL - 1 : rr);
            src = &Rb[((size_t)(b * RL + rr) * NH + n) * DH + ch * 8];
        }
        *(uint4*)&sKR[row * SPAD + ch * 8] = *(const uint4*)src;
    }
    __syncthreads();

    f32x4 acc[12];
    #pragma unroll
    for (int i = 0; i < 12; ++i) acc[i] = (f32x4){0.f, 0.f, 0.f, 0.f};
    #pragma unroll
    for (int ks = 0; ks < 2; ++ks) {
        bf16x8 a = *(const bf16x8*)&sQ[(w * 16 + lr) * SPAD + ks * 32 + quad * 8];
        #pragma unroll
        for (int ct = 0; ct < 12; ++ct) {
            bf16x8 bfrag = *(const bf16x8*)&sKR[(ct * 16 + lr) * SPAD + ks * 32 + quad * 8];
            acc[ct] = __builtin_amdgcn_mfma_f32_16x16x32_bf16(a, bfrag, acc[ct], 0, 0, 0);
        }
    }

    float* myD = &sD2[w * 16 * 132];
    #pragma unroll
    for (int ct = 4; ct < 12; ++ct) {
        int pt = (ct - 4) * 16;
        #pragma unroll
        for (int r = 0; r < 4; ++r)
            myD[(quad * 4 + r) * 132 + pt + lr] = acc[ct][r];
    }
    __syncthreads();

    const int f32 = flags[0], s32 = flags[1];
    #pragma unroll
    for (int ct = 0; ct < 4; ++ct) {
        int jl = ct * 16 + lr, j = j0 + jl;
        float ckv = CK[(size_t)bn * CL + j];
        #pragma unroll
        for (int r = 0; r < 4; ++r) {
            int ilw = quad * 4 + r;
            int il = w * 16 + ilw;
            int i = i0 + il;
            int p = 63 - il + jl;            // in [0,126]
            float bd = myD[ilw * 132 + p];
            float pr = PR[(size_t)bn * RL + baseR + p];
            size_t mi = ((size_t)b * QL + i) * CL + j;
            int sv = s32 ? ((const int*)seg)[mi] : (int)((const signed char*)seg)[mi];
            float ef = EF[((size_t)bn * QL + i) * 2 + (sv ? 1 : 0)];
            float mk = f32 ? maskf[mi] : b2f(maskb[mi]);
            SC[((size_t)bn * QL + i) * CL + j] =
                (acc[ct][r] + bd + ckv + pr + ef) * 0.125f + mk * -1e30f;
        }
    }
}

// ---------------- softmax (CL=1024): fp32 in, bf16 probs in-place ----------------
__global__ __launch_bounds__(256) void softmax_kernel(float* __restrict__ SC) {
    const int row = blockIdx.x;
    float* p = SC + (size_t)row * CL;
    const int tid = threadIdx.x;
    const int wid = tid >> 6, lane = tid & 63;
    __shared__ float r1[4], r2[4];
    float v[4];
    #pragma unroll
    for (int c = 0; c < 4; ++c) v[c] = p[c * 256 + tid];
    float mx = fmaxf(fmaxf(v[0], v[1]), fmaxf(v[2], v[3]));
    #pragma unroll
    for (int o = 32; o > 0; o >>= 1) mx = fmaxf(mx, __shfl_xor(mx, o));
    if (lane == 0) r1[wid] = mx;
    __syncthreads();
    mx = fmaxf(fmaxf(r1[0], r1[1]), fmaxf(r1[2], r1[3]));
    float s = 0.f;
    #pragma unroll
    for (int c = 0; c < 4; ++c) { v[c] = __expf(v[c] - mx); s += v[c]; }
    #pragma unroll
    for (int o = 32; o > 0; o >>= 1) s += __shfl_xor(s, o);
    if (lane == 0) r2[wid] = s;
    __syncthreads();
    s = r2[0] + r2[1] + r2[2] + r2[3];
    float inv = 1.0f / s;
    u16* pb = (u16*)p;
    #pragma unroll
    for (int c = 0; c < 4; ++c) pb[c * 256 + tid] = f2u(v[c] * inv);
}

// ---------------- MFMA attn = probs(bf16) @ V, per (b,n) ----------------
#define VPAD 40
__global__ __launch_bounds__(256) void attn_v_mfma(
    const u16* __restrict__ PB, const u16* __restrict__ Vb, u16* __restrict__ AT)
{
    __shared__ __align__(16) u16 sP[32 * VPAD];
    __shared__ __align__(16) u16 sV[64 * VPAD];
    const int tid = threadIdx.x;
    const int i0 = blockIdx.x * 32;
    const int bn = blockIdx.y, b = bn >> 4, n = bn & 15;
    const int lane = tid & 63, w = tid >> 6;
    const int lr = lane & 15, quad = lane >> 4;
    const int rt = w >> 1;
    const int ct0 = (w & 1) * 2;
    const u16* Prow = PB + (size_t)bn * QL * 2 * CL;
    f32x4 acc[2];
    acc[0] = (f32x4){0.f, 0.f, 0.f, 0.f};
    acc[1] = (f32x4){0.f, 0.f, 0.f, 0.f};

    for (int k0 = 0; k0 < CL; k0 += 32) {
        if (tid < 128) {
            int row = tid >> 2, ch = tid & 3;
            *(uint4*)&sP[row * VPAD + ch * 8] =
                *(const uint4*)&Prow[(size_t)(i0 + row) * 2 * CL + k0 + ch * 8];
        }
        {
            int j = tid >> 3, d0 = (tid & 7) * 8;
            u16 tmp[8];
            *(uint4*)tmp = *(const uint4*)&Vb[((size_t)(b * CL + k0 + j) * NH + n) * DH + d0];
            #pragma unroll
            for (int q2 = 0; q2 < 8; ++q2) sV[(d0 + q2) * VPAD + j] = tmp[q2];
        }
        __syncthreads();
        bf16x8 a = *(const bf16x8*)&sP[(rt * 16 + lr) * VPAD + quad * 8];
        #pragma unroll
        for (int c = 0; c < 2; ++c) {
            bf16x8 bfrag = *(const bf16x8*)&sV[((ct0 + c) * 16 + lr) * VPAD + quad * 8];
            acc[c] = __builtin_amdgcn_mfma_f32_16x16x32_bf16(a, bfrag, acc[c], 0, 0, 0);
        }
        __syncthreads();
    }
    #pragma unroll
    for (int c = 0; c < 2; ++c) {
        int d = (ct0 + c) * 16 + lr;
        #pragma unroll
        for (int r = 0; r < 4; ++r) {
            int i = i0 + rt * 16 + quad * 4 + r;
            AT[((size_t)(b * QL + i) * NH + n) * DH + d] = f2u(acc[c][r]);
        }
    }
}

extern "C" void kernel_launch(void* const* d_in, const int* in_sizes, int n_in,
                              void* d_out, int out_size, void* d_ws, size_t ws_size,
                              hipStream_t stream) {
    (void)in_sizes; (void)n_in; (void)out_size; (void)ws_size;
    const void* content_stream = d_in[0];
    const void* content_mask   = d_in[1];
    const void* pos_enc        = d_in[2];
    const void* seg_mat        = d_in[3];
    const void* mems           = d_in[4];
    const void* w_q            = d_in[5];
    const void* w_k            = d_in[6];
    const void* w_v            = d_in[7];
    const void* w_r            = d_in[8];
    const void* w_o            = d_in[9];
    const void* ffn_w1         = d_in[10];
    const void* ffn_b1         = d_in[11];
    const void* ffn_w2         = d_in[12];
    const void* ffn_b2         = d_in[13];
    const void* ln1_g          = d_in[14];
    const void* ln1_b          = d_in[15];
    const void* ln2_g          = d_in[16];
    const void* ln2_b          = d_in[17];
    const void* cb             = d_in[18];
    const void* pb             = d_in[19];
    const void* sb             = d_in[20];
    const void* se             = d_in[21];

    float* SC    = (float*)d_ws;              // scores / bf16 probs / F1 / PART
    float* PART  = SC + 4194304;              // 4M f32 partials (probs dead by then)
    float* EF    = SC + 16777216;
    float* CK    = EF + 32768;
    float* PR    = CK + 32768;
    int*   flags = (int*)(PR + 49152);
    u16*   bws   = (u16*)(flags + 16);

    u16* X   = bws;               u16* Y   = X   + 1048576;
    u16* CTX = Y   + 1048576;     u16* Qb  = CTX + 2097152;
    u16* Kb  = Qb  + 1048576;     u16* Vb  = Kb  + 2097152;
    u16* Rb  = Vb  + 2097152;     u16* PE  = Rb  + 3145728;
    u16* AT  = PE  + 3145728;
    u16* W4  = AT  + 1048576;     // WQT|WKT|WVT|WRT contiguous
    u16* WOc = W4  + 4194304;     u16* W1T = WOc + 1048576;
    u16* W2T = W1T + 4194304;
    u16* F1  = (u16*)SC;          // alias: probs/scores consumed before FFN1 writes

    const size_t wstride   = (size_t)HD * HD;
    const size_t memstride = (size_t)BQ * ML * HD;

    const dim3 blk(256);
    #define DUAL(base, off) ((FP)(base) + (off)), ((BP)(base) + (off))

    sniff_kernel<<<dim3(1), dim3(64), 0, stream>>>(
        (const unsigned int*)ln1_g, (const unsigned char*)seg_mat, flags);

    canon_kernel<<<dim3((BQ * QL * HD) / 256), blk, 0, stream>>>(
        DUAL(content_stream, 0), X, BQ * QL * HD, flags);
    canon_kernel<<<dim3((BQ * RL * HD) / 256), blk, 0, stream>>>(
        DUAL(pos_enc, 0), PE, BQ * RL * HD, flags);

    for (int l = 0; l < NLAYER; ++l) {
        transpose_kernel<<<dim3(32, 32), blk, 0, stream>>>(
            DUAL(w_q, (size_t)l * wstride), W4, HD, HD, flags);
        transpose_kernel<<<dim3(32, 32), blk, 0, stream>>>(
            DUAL(w_k, (size_t)l * wstride), W4 + 1048576, HD, HD, flags);
        transpose_kernel<<<dim3(32, 32), blk, 0, stream>>>(
            DUAL(w_v, (size_t)l * wstride), W4 + 2097152, HD, HD, flags);
        transpose_kernel<<<dim3(32, 32), blk, 0, stream>>>(
            DUAL(w_r, (size_t)l * wstride), W4 + 3145728, HD, HD, flags);
        canon_kernel<<<dim3((HD * HD) / 256), blk, 0, stream>>>(
            DUAL(w_o, (size_t)l * wstride), WOc, HD * HD, flags);
        transpose_kernel<<<dim3(FF / 32, HD / 32), blk, 0, stream>>>(
            DUAL(ffn_w1, (size_t)l * HD * FF), W1T, HD, FF, flags);
        transpose_kernel<<<dim3(HD / 32, FF / 32), blk, 0, stream>>>(
            DUAL(ffn_w2, (size_t)l * FF * HD), W2T, FF, HD, flags);

        build_ctx_kernel<<<dim3((BQ * CL * HD) / 256), blk, 0, stream>>>(
            DUAL(mems, (size_t)l * memstride), X, CTX, flags);

        proj4_gemm<<<dim3(8, 64), blk, 0, stream>>>(
            X, CTX, PE, W4, Qb, Kb, Vb, Rb);

        ef2_kernel<<<dim3((BQ * NH * QL) / 256), blk, 0, stream>>>(
            Qb, DUAL(sb, 0), DUAL(se, (size_t)l * 2 * NH * DH), EF, flags);
        ckpr_kernel<<<dim3((32 * CL + 32 * RL) / 256), blk, 0, stream>>>(
            Kb, Rb, DUAL(cb, 0), DUAL(pb, 0), CK, PR, flags);

        scores_mfma<<<dim3(CL / 64, QL / 64, BQ * NH), blk, 0, stream>>>(
            Qb, Kb, Rb, CK, PR, EF, seg_mat, DUAL(content_mask, 0), SC, flags);

        softmax_kernel<<<dim3(BQ * NH * QL), blk, 0, stream>>>(SC);

        attn_v_mfma<<<dim3(QL / 32, BQ * NH), blk, 0, stream>>>(
            (const u16*)SC, Vb, AT);

        gemm128_splitk<<<dim3(8, 8, 4), blk, 0, stream>>>(
            AT, WOc, PART, HD, HD, 256);
        reduce_add_ln<false><<<dim3(BQ * QL), blk, 0, stream>>>(
            PART, (FP)nullptr, (BP)nullptr, X,
            DUAL(ln1_g, (size_t)l * HD), DUAL(ln1_b, (size_t)l * HD), Y, flags);

        mfma_gemm128<true, true><<<dim3(FF / 128, (BQ * QL) / 128), blk, 0, stream>>>(
            Y, W1T, DUAL(ffn_b1, (size_t)l * FF), F1, FF, HD, flags);

        gemm128_splitk<<<dim3(8, 8, 4), blk, 0, stream>>>(
            F1, W2T, PART, HD, FF, 1024);
        reduce_add_ln<true><<<dim3(BQ * QL), blk, 0, stream>>>(
            PART, DUAL(ffn_b2, (size_t)l * HD), Y,
            DUAL(ln2_g, (size_t)l * HD), DUAL(ln2_b, (size_t)l * HD), X, flags);
    }
    #undef DUAL

    out_write_kernel<<<dim3((BQ * QL * HD) / 256), blk, 0, stream>>>(
        X, d_out, BQ * QL * HD, flags);
}